// Round 4
// baseline (4656.282 us; speedup 1.0000x reference)
//
#include <hip/hip_runtime.h>
#include <cmath>

// VQ-VAE quantization forward: B=64, K=1024, D=128, H=W=32.
// Ref model (6 rounds of absmax triangulation): q_k = fl32(fl32(A - fl32(2*B_k)) + C_k),
// first-index argmin, B = single-accumulator SEQUENTIAL FMA over d.
// A = sum(z*z,-1) sequential; C = sum(emb*emb,-1) pairwise-8.
// out0 = fl(fl(e-z)+z); out1 = e. Exact chains pinned with empty-asm barriers.
//
// R4: coarse scoring moves to the matrix pipe. R3 was LDS-pipe-bound (8 e-broadcast
// ds_read_b128 per g deliver 16B payload each at ~12cyc of the CU-shared pipe =>
// 3.75x oversubscribed, VALUBusy 25%). New scheme:
//  * prologue kernel converts emb to bf16 (RNE) into d_ws (256KB).
//  * main kernel: per wave, z-frags (16 px x 128 d, bf16) built once into 16 VGPRs;
//    hot loop per 16-code tile: 4 global b128 (bf16 e-frags) + 4 chained MFMA
//    (16x16x32_bf16) + ~10 VALU. Zero LDS traffic in the hot loop.
//  * pass 1: per-px coarse min via 16-lane shfl_xor reduce.
//  * pass 2: identical recompute (bitwise-deterministic), collect codes with
//    t <= gmin + TH into per-px LDS worklist (atomicAdd slots, CAP=16,
//    full-scan fallback on overflow).
//  * refinement: EXACT ref chains (verbatim from validated kernel) over the
//    worklist; first-index tie-break. Coarse error eps <= sum|z*e|*2^-8 ~ 2-4e-4;
//    TH=4e-3 >= 4x the 2*(eps+chain-delta) requirement.
//  * Operand-layout safety: A and B frags loaded with the SAME (l&15, l>>4)
//    d-bijection => per-lane k-order uncertainty cancels; C/D map is the
//    HW-verified col=lane&15(code), row=(lane>>4)*4+reg(px).
// snorm / A32 / B-chain / output chains bit-identical to the validated kernel.

#define D_DIM   128
#define K_CODES 1024
#define HW_SZ   1024
#define N_PIX   65536
#define OUT_OFF ((size_t)N_PIX * D_DIM)

#define PXB     128                     // pixels per block
#define NW      8                       // waves per block
#define NTILE   (K_CODES / 16)          // 64 code-tiles
#define ZLD     132                     // padded z row (floats)
#define TH      4.0e-3f                 // coarse candidate window
#define CAP     16                      // worklist capacity per pixel

typedef float  f32x4 __attribute__((ext_vector_type(4)));
typedef short  s16x8 __attribute__((ext_vector_type(8)));
typedef unsigned short u16x8 __attribute__((ext_vector_type(8)));

// --- compiler-proof fp32 ops: result pinned in a VGPR via empty asm ---
__device__ __forceinline__ float fmul_x(float a, float b) {
    float r = a * b; asm volatile("" : "+v"(r)); return r;
}
__device__ __forceinline__ float fadd_x(float a, float b) {
    float r = a + b; asm volatile("" : "+v"(r)); return r;
}
__device__ __forceinline__ float fsub_x(float a, float b) {
    float r = a - b; asm volatile("" : "+v"(r)); return r;
}
__device__ __forceinline__ float ffma_x(float a, float b, float c) {
    float r = fmaf(a, b, c); asm volatile("" : "+v"(r)); return r;
}

// RNE float -> bf16 bits (inputs are normal floats here)
__device__ __forceinline__ unsigned short f2bf(float f) {
    unsigned u = __float_as_uint(f);
    u += 0x7FFFu + ((u >> 16) & 1u);
    return (unsigned short)(u >> 16);
}

// ---- prologue: emb fp32 -> bf16 table in workspace ----
__global__ __launch_bounds__(256) void conv_ebf(
    const float* __restrict__ emb, unsigned short* __restrict__ ebf)
{
    const int i = (blockIdx.x * 256 + threadIdx.x) * 8;   // 64*256*8 = 131072
    const f32x4 a = *(const f32x4*)(emb + i);
    const f32x4 b = *(const f32x4*)(emb + i + 4);
    u16x8 o;
    o[0] = f2bf(a[0]); o[1] = f2bf(a[1]); o[2] = f2bf(a[2]); o[3] = f2bf(a[3]);
    o[4] = f2bf(b[0]); o[5] = f2bf(b[1]); o[6] = f2bf(b[2]); o[7] = f2bf(b[3]);
    *(u16x8*)(ebf + i) = o;
}

__global__ __launch_bounds__(512, 2) void vq_fused(
    const float* __restrict__ z_e,
    const float* __restrict__ emb,
    const unsigned short* __restrict__ ebf,
    float* __restrict__ out)
{
#pragma clang fp contract(off)
    __shared__ float s_zT[PXB][ZLD];            // 66 KB fp32 z, [px][d]
    __shared__ float snorm[K_CODES];            // 4 KB
    __shared__ int   s_cnt[PXB];                // worklist counters
    __shared__ int   s_ck[PXB][CAP];            // 8 KB worklist codes
    __shared__ int   s_kwin[PXB];

    const int px  = threadIdx.x;                // lane 0..63
    const int ky  = threadIdx.y;                // wave 0..7
    const int tid = ky * 64 + px;

    const int p0  = blockIdx.x * PXB;
    const int b   = p0 >> 10;
    const int hw0 = p0 & (HW_SZ - 1);
    const float* zbase = z_e + (size_t)b * (D_DIM * HW_SZ) + hw0;

    if (tid < PXB) s_cnt[tid] = 0;

    // ---- z stage: global [d][128 px] -> s_zT[px][d] (transpose) ----
    #pragma unroll
    for (int r = 0; r < 8; ++r) {
        const int idx = r * 512 + tid;          // 0..4095
        const int d   = idx >> 5;               // 0..127
        const int i4  = (idx & 31) * 4;         // pixel group
        const f32x4 v = *(const f32x4*)(zbase + (size_t)d * HW_SZ + i4);
        s_zT[i4 + 0][d] = v[0];
        s_zT[i4 + 1][d] = v[1];
        s_zT[i4 + 2][d] = v[2];
        s_zT[i4 + 3][d] = v[3];
    }

    // ---- C_k = np.sum(emb*emb,-1): pairwise-8 (n=128), chain verbatim ----
    for (int k = tid; k < K_CODES; k += NW * 64) {
        const float* row = emb + (size_t)k * D_DIM;
        float r[8];
        #pragma unroll
        for (int j = 0; j < 8; ++j) r[j] = fmul_x(row[j], row[j]);
        for (int i = 8; i < D_DIM; i += 8) {
            #pragma unroll
            for (int j = 0; j < 8; ++j)
                r[j] = fadd_x(r[j], fmul_x(row[i + j], row[i + j]));
        }
        const float s01 = fadd_x(r[0], r[1]), s23 = fadd_x(r[2], r[3]);
        const float s45 = fadd_x(r[4], r[5]), s67 = fadd_x(r[6], r[7]);
        snorm[k] = fadd_x(fadd_x(s01, s23), fadd_x(s45, s67));
    }
    __syncthreads();

    // ---- build A-frags: wave ky owns px rows [ky*16, ky*16+16) ----
    const int lm = px & 15;                     // 16-index (A row / B col)
    const int lg = px >> 4;                     // d-slice group 0..3
    const int pxbase = ky * 16;

    s16x8 afr[4];
    #pragma unroll
    for (int dt = 0; dt < 4; ++dt) {
        const float* zr = &s_zT[pxbase + lm][dt * 32 + lg * 8];
        const f32x4 z0 = *(const f32x4*)zr;
        const f32x4 z1 = *(const f32x4*)(zr + 4);
        s16x8 a;
        a[0] = (short)f2bf(z0[0]); a[1] = (short)f2bf(z0[1]);
        a[2] = (short)f2bf(z0[2]); a[3] = (short)f2bf(z0[3]);
        a[4] = (short)f2bf(z1[0]); a[5] = (short)f2bf(z1[1]);
        a[6] = (short)f2bf(z1[2]); a[7] = (short)f2bf(z1[3]);
        afr[dt] = a;
    }

    // ---- pass 1: coarse min per pixel ----
    float m0 = __builtin_inff(), m1 = m0, m2 = m0, m3 = m0;
    #pragma unroll 2
    for (int T = 0; T < NTILE; ++T) {
        const int code = T * 16 + lm;
        const unsigned short* eb = ebf + (size_t)code * D_DIM + lg * 8;
        const s16x8 b0 = *(const s16x8*)(eb);
        const s16x8 b1 = *(const s16x8*)(eb + 32);
        const s16x8 b2 = *(const s16x8*)(eb + 64);
        const s16x8 b3 = *(const s16x8*)(eb + 96);
        f32x4 acc = {0.f, 0.f, 0.f, 0.f};
        acc = __builtin_amdgcn_mfma_f32_16x16x32_bf16(afr[0], b0, acc, 0, 0, 0);
        acc = __builtin_amdgcn_mfma_f32_16x16x32_bf16(afr[1], b1, acc, 0, 0, 0);
        acc = __builtin_amdgcn_mfma_f32_16x16x32_bf16(afr[2], b2, acc, 0, 0, 0);
        acc = __builtin_amdgcn_mfma_f32_16x16x32_bf16(afr[3], b3, acc, 0, 0, 0);
        const float sn = snorm[code];
        m0 = fminf(m0, fmaf(-2.f, acc[0], sn));
        m1 = fminf(m1, fmaf(-2.f, acc[1], sn));
        m2 = fminf(m2, fmaf(-2.f, acc[2], sn));
        m3 = fminf(m3, fmaf(-2.f, acc[3], sn));
    }
    // reduce across the 16 lanes sharing each px row (xor masks stay in-group)
    float gm[4] = {m0, m1, m2, m3};
    #pragma unroll
    for (int r = 0; r < 4; ++r) {
        #pragma unroll
        for (int mask = 1; mask < 16; mask <<= 1)
            gm[r] = fminf(gm[r], __shfl_xor(gm[r], mask, 64));
    }

    // ---- pass 2: identical recompute, collect candidates within TH ----
    #pragma unroll 2
    for (int T = 0; T < NTILE; ++T) {
        const int code = T * 16 + lm;
        const unsigned short* eb = ebf + (size_t)code * D_DIM + lg * 8;
        const s16x8 b0 = *(const s16x8*)(eb);
        const s16x8 b1 = *(const s16x8*)(eb + 32);
        const s16x8 b2 = *(const s16x8*)(eb + 64);
        const s16x8 b3 = *(const s16x8*)(eb + 96);
        f32x4 acc = {0.f, 0.f, 0.f, 0.f};
        acc = __builtin_amdgcn_mfma_f32_16x16x32_bf16(afr[0], b0, acc, 0, 0, 0);
        acc = __builtin_amdgcn_mfma_f32_16x16x32_bf16(afr[1], b1, acc, 0, 0, 0);
        acc = __builtin_amdgcn_mfma_f32_16x16x32_bf16(afr[2], b2, acc, 0, 0, 0);
        acc = __builtin_amdgcn_mfma_f32_16x16x32_bf16(afr[3], b3, acc, 0, 0, 0);
        const float sn = snorm[code];
        #pragma unroll
        for (int r = 0; r < 4; ++r) {
            const float t = fmaf(-2.f, acc[r], sn);
            if (t <= gm[r] + TH) {
                const int prow = pxbase + lg * 4 + r;   // C/D row -> pixel
                const int slot = atomicAdd(&s_cnt[prow], 1);
                if (slot < CAP) s_ck[prow][slot] = code;
            }
        }
    }
    __syncthreads();

    // ---- exact refinement (waves 0-1): ref chains verbatim ----
    if (ky < 2) {
        const int p = ky * 64 + px;
        // A: sequential over d (value cancels per-pixel; chain kept honest).
        const float z0 = s_zT[p][0];
        float A32 = fmul_x(z0, z0);
        for (int d = 1; d < D_DIM; ++d) {
            const float zd = s_zT[p][d];
            A32 = fadd_x(A32, fmul_x(zd, zd));
        }

        float bestq = __builtin_inff(); int bestk = 0x7fffffff;
        const int cnt = s_cnt[p];
        if (cnt <= CAP) {
            for (int i = 0; i < cnt; ++i) {
                const int kc = s_ck[p][i];
                const float* e = emb + (size_t)kc * D_DIM;
                float B32 = 0.f;
                for (int d = 0; d < D_DIM; ++d)
                    B32 = ffma_x(s_zT[p][d], e[d], B32);
                const float twoB = fmul_x(2.0f, B32);          // exact
                const float q    = fadd_x(fsub_x(A32, twoB), snorm[kc]);
                if (q < bestq || (q == bestq && kc < bestk)) { bestq = q; bestk = kc; }
            }
        } else {
            // worklist overflow (P ~ 1e-12/px): exact full scan, still correct
            for (int kc = 0; kc < K_CODES; ++kc) {
                const float* e = emb + (size_t)kc * D_DIM;
                float B32 = 0.f;
                for (int d = 0; d < D_DIM; ++d)
                    B32 = ffma_x(s_zT[p][d], e[d], B32);
                const float twoB = fmul_x(2.0f, B32);
                const float q    = fadd_x(fsub_x(A32, twoB), snorm[kc]);
                if (q < bestq || (q == bestq && kc < bestk)) { bestq = q; bestk = kc; }
            }
        }
        s_kwin[p] = bestk;
    }
    __syncthreads();

    // ---- epilogue: out0 = fl(fl(e-z)+z) (pinned), out1 = e ----
    const int p  = tid & 127;                   // pixel
    const int dg = tid >> 7;                    // d-quarter 0..3
    const int kwin = s_kwin[p];
    const float* er = emb + (size_t)kwin * D_DIM + dg * 32;
    float* o0 = out + (size_t)b * (D_DIM * HW_SZ) + hw0 + p;
    float* o1 = o0 + OUT_OFF;
    #pragma unroll
    for (int i = 0; i < 8; ++i) {
        const f32x4 e4 = *(const f32x4*)(er + i * 4);
        #pragma unroll
        for (int j = 0; j < 4; ++j) {
            const int d = dg * 32 + i * 4 + j;
            const float zv = s_zT[p][d];
            o0[(size_t)d * HW_SZ] = fadd_x(fsub_x(e4[j], zv), zv);
            o1[(size_t)d * HW_SZ] = e4[j];
        }
    }
}

extern "C" void kernel_launch(void* const* d_in, const int* in_sizes, int n_in,
                              void* d_out, int out_size, void* d_ws, size_t ws_size,
                              hipStream_t stream)
{
    const float* z_e = (const float*)d_in[0];
    const float* emb = (const float*)d_in[1];
    float* out = (float*)d_out;
    unsigned short* ebf = (unsigned short*)d_ws;
    (void)in_sizes; (void)n_in; (void)out_size; (void)ws_size;

    conv_ebf<<<dim3(64), dim3(256), 0, stream>>>(emb, ebf);
    vq_fused<<<dim3(N_PIX / PXB), dim3(64, NW), 0, stream>>>(z_e, emb, ebf, out);
}

// Round 5
// 4489.216 us; speedup vs baseline: 1.0372x; 1.0372x over previous
//
#include <hip/hip_runtime.h>
#include <cmath>

// VQ-VAE quantization forward: B=64, K=1024, D=128, H=W=32.
// Ref model (6 rounds of absmax triangulation): q_k = fl32(fl32(A - fl32(2*B_k)) + C_k),
// first-index argmin, B = single-accumulator SEQUENTIAL FMA over d.
// A = sum(z*z,-1) sequential; C = sum(emb*emb,-1) pairwise-8.
// out0 = fl(fl(e-z)+z); out1 = e. Exact chains pinned with empty-asm barriers.
//
// R5: R4 (MFMA coarse + exact refinement) was CORRECT (absmax 0) but fell into a
// memory-latency pit: VGPR=52 => zero tiles in flight, and the per-lane e-frag
// loads were scattered (16 cache lines @256B stride per b128) => ~10K cyc/tile,
// all pipes <1% busy, 4.6ms. Fix, feed only:
//  * prologue writes the bf16 table TILED: ebt[((T*4+dt)*64+lane)*8] = the exact
//    fragment lane needs => each hot-loop load is one coalesced 1KB dwordx4.
//  * explicit 2-tile software pipeline (rotating regs), __launch_bounds__(512,4)
//    (VGPR cap 128) so next-tile loads fly under current-tile MFMAs.
//  * split accumulators (two 2-MFMA chains summed once): halves dep latency.
//    Coarse t = fmaf(-2, a0[r]+a1[r], sn) — identical expression tree in both
//    passes => bitwise-consistent min/collect; TH covers bf16+assoc error.
// Unchanged from the PASSING R4: snorm pairwise-8 chain, A/B exact pinned
// chains, first-index tie-break, TH=4e-3, CAP=16 + full-scan fallback,
// C/D map col=lane&15(code), row=(lane>>4)*4+reg(px), epilogue chains.

#define D_DIM   128
#define K_CODES 1024
#define HW_SZ   1024
#define N_PIX   65536
#define OUT_OFF ((size_t)N_PIX * D_DIM)

#define PXB     128                     // pixels per block
#define NW      8                       // waves per block
#define NTILE   (K_CODES / 16)          // 64 code-tiles
#define ZLD     132                     // padded z row (floats)
#define TH      4.0e-3f                 // coarse candidate window
#define CAP     16                      // worklist capacity per pixel

typedef float  f32x4 __attribute__((ext_vector_type(4)));
typedef short  s16x8 __attribute__((ext_vector_type(8)));
typedef unsigned short u16x8 __attribute__((ext_vector_type(8)));

// --- compiler-proof fp32 ops: result pinned in a VGPR via empty asm ---
__device__ __forceinline__ float fmul_x(float a, float b) {
    float r = a * b; asm volatile("" : "+v"(r)); return r;
}
__device__ __forceinline__ float fadd_x(float a, float b) {
    float r = a + b; asm volatile("" : "+v"(r)); return r;
}
__device__ __forceinline__ float fsub_x(float a, float b) {
    float r = a - b; asm volatile("" : "+v"(r)); return r;
}
__device__ __forceinline__ float ffma_x(float a, float b, float c) {
    float r = fmaf(a, b, c); asm volatile("" : "+v"(r)); return r;
}

// RNE float -> bf16 bits (inputs are normal floats here)
__device__ __forceinline__ unsigned short f2bf(float f) {
    unsigned u = __float_as_uint(f);
    u += 0x7FFFu + ((u >> 16) & 1u);
    return (unsigned short)(u >> 16);
}

// ---- prologue: emb fp32 -> TILED bf16 fragment table in workspace ----
// ebt[((T*4+dt)*64 + l)*8 + j] = bf16(emb[T*16 + (l&15)][dt*32 + ((l>>4)&3)*8 + j])
__global__ __launch_bounds__(256) void conv_ebf(
    const float* __restrict__ emb, unsigned short* __restrict__ ebt)
{
    const int t  = blockIdx.x * 256 + threadIdx.x;   // 0..16383
    const int l  = t & 63;
    const int dt = (t >> 6) & 3;
    const int T  = t >> 8;
    const int code = T * 16 + (l & 15);
    const int d0   = dt * 32 + ((l >> 4) & 3) * 8;
    const float* src = emb + (size_t)code * D_DIM + d0;
    const f32x4 a = *(const f32x4*)(src);
    const f32x4 b = *(const f32x4*)(src + 4);
    u16x8 o;
    o[0] = f2bf(a[0]); o[1] = f2bf(a[1]); o[2] = f2bf(a[2]); o[3] = f2bf(a[3]);
    o[4] = f2bf(b[0]); o[5] = f2bf(b[1]); o[6] = f2bf(b[2]); o[7] = f2bf(b[3]);
    *(u16x8*)(ebt + (size_t)t * 8) = o;
}

__global__ __launch_bounds__(512, 4) void vq_fused(
    const float* __restrict__ z_e,
    const float* __restrict__ emb,
    const unsigned short* __restrict__ ebt,
    float* __restrict__ out)
{
#pragma clang fp contract(off)
    __shared__ float s_zT[PXB][ZLD];            // 66 KB fp32 z, [px][d]
    __shared__ float snorm[K_CODES];            // 4 KB
    __shared__ int   s_cnt[PXB];                // worklist counters
    __shared__ int   s_ck[PXB][CAP];            // 8 KB worklist codes
    __shared__ int   s_kwin[PXB];

    const int px  = threadIdx.x;                // lane 0..63
    const int ky  = threadIdx.y;                // wave 0..7
    const int tid = ky * 64 + px;

    const int p0  = blockIdx.x * PXB;
    const int b   = p0 >> 10;
    const int hw0 = p0 & (HW_SZ - 1);
    const float* zbase = z_e + (size_t)b * (D_DIM * HW_SZ) + hw0;

    if (tid < PXB) s_cnt[tid] = 0;

    // ---- z stage: global [d][128 px] -> s_zT[px][d] (transpose) ----
    #pragma unroll
    for (int r = 0; r < 8; ++r) {
        const int idx = r * 512 + tid;          // 0..4095
        const int d   = idx >> 5;               // 0..127
        const int i4  = (idx & 31) * 4;         // pixel group
        const f32x4 v = *(const f32x4*)(zbase + (size_t)d * HW_SZ + i4);
        s_zT[i4 + 0][d] = v[0];
        s_zT[i4 + 1][d] = v[1];
        s_zT[i4 + 2][d] = v[2];
        s_zT[i4 + 3][d] = v[3];
    }

    // ---- C_k = np.sum(emb*emb,-1): pairwise-8 (n=128), chain verbatim ----
    for (int k = tid; k < K_CODES; k += NW * 64) {
        const float* row = emb + (size_t)k * D_DIM;
        float r[8];
        #pragma unroll
        for (int j = 0; j < 8; ++j) r[j] = fmul_x(row[j], row[j]);
        for (int i = 8; i < D_DIM; i += 8) {
            #pragma unroll
            for (int j = 0; j < 8; ++j)
                r[j] = fadd_x(r[j], fmul_x(row[i + j], row[i + j]));
        }
        const float s01 = fadd_x(r[0], r[1]), s23 = fadd_x(r[2], r[3]);
        const float s45 = fadd_x(r[4], r[5]), s67 = fadd_x(r[6], r[7]);
        snorm[k] = fadd_x(fadd_x(s01, s23), fadd_x(s45, s67));
    }
    __syncthreads();

    // ---- build A-frags: wave ky owns px rows [ky*16, ky*16+16) ----
    const int lm = px & 15;                     // 16-index (A row / B col)
    const int lg = px >> 4;                     // d-slice group 0..3
    const int pxbase = ky * 16;

    s16x8 afr[4];
    #pragma unroll
    for (int dt = 0; dt < 4; ++dt) {
        const float* zr = &s_zT[pxbase + lm][dt * 32 + lg * 8];
        const f32x4 z0 = *(const f32x4*)zr;
        const f32x4 z1 = *(const f32x4*)(zr + 4);
        s16x8 a;
        a[0] = (short)f2bf(z0[0]); a[1] = (short)f2bf(z0[1]);
        a[2] = (short)f2bf(z0[2]); a[3] = (short)f2bf(z0[3]);
        a[4] = (short)f2bf(z1[0]); a[5] = (short)f2bf(z1[1]);
        a[6] = (short)f2bf(z1[2]); a[7] = (short)f2bf(z1[3]);
        afr[dt] = a;
    }

    // lane-fixed base into the tiled fragment table
    const unsigned short* tbase = ebt + (size_t)px * 8;
    // frag (T,dt) for this lane: tbase + (T*256 + dt*64)*8 shorts

    // ================= pass 1: coarse min per pixel =================
    float m0 = __builtin_inff(), m1 = m0, m2 = m0, m3 = m0;
    {
        s16x8 c0 = *(const s16x8*)(tbase + 0);
        s16x8 c1 = *(const s16x8*)(tbase + 64 * 8);
        s16x8 c2 = *(const s16x8*)(tbase + 128 * 8);
        s16x8 c3 = *(const s16x8*)(tbase + 192 * 8);
        #pragma unroll 1
        for (int T = 0; T < NTILE; ++T) {
            const int Tn = (T + 1) & (NTILE - 1);
            const size_t nb = (size_t)Tn * 256 * 8;
            const s16x8 n0 = *(const s16x8*)(tbase + nb);
            const s16x8 n1 = *(const s16x8*)(tbase + nb + 64 * 8);
            const s16x8 n2 = *(const s16x8*)(tbase + nb + 128 * 8);
            const s16x8 n3 = *(const s16x8*)(tbase + nb + 192 * 8);
            f32x4 a0 = {0.f, 0.f, 0.f, 0.f};
            f32x4 a1 = {0.f, 0.f, 0.f, 0.f};
            a0 = __builtin_amdgcn_mfma_f32_16x16x32_bf16(afr[0], c0, a0, 0, 0, 0);
            a0 = __builtin_amdgcn_mfma_f32_16x16x32_bf16(afr[1], c1, a0, 0, 0, 0);
            a1 = __builtin_amdgcn_mfma_f32_16x16x32_bf16(afr[2], c2, a1, 0, 0, 0);
            a1 = __builtin_amdgcn_mfma_f32_16x16x32_bf16(afr[3], c3, a1, 0, 0, 0);
            const float sn = snorm[T * 16 + lm];
            m0 = fminf(m0, fmaf(-2.f, a0[0] + a1[0], sn));
            m1 = fminf(m1, fmaf(-2.f, a0[1] + a1[1], sn));
            m2 = fminf(m2, fmaf(-2.f, a0[2] + a1[2], sn));
            m3 = fminf(m3, fmaf(-2.f, a0[3] + a1[3], sn));
            c0 = n0; c1 = n1; c2 = n2; c3 = n3;
        }
    }
    // reduce across the 16 lanes sharing each px row (xor masks stay in-group)
    float gm[4] = {m0, m1, m2, m3};
    #pragma unroll
    for (int r = 0; r < 4; ++r) {
        #pragma unroll
        for (int mask = 1; mask < 16; mask <<= 1)
            gm[r] = fminf(gm[r], __shfl_xor(gm[r], mask, 64));
    }

    // ====== pass 2: bitwise-identical recompute, collect within TH ======
    {
        s16x8 c0 = *(const s16x8*)(tbase + 0);
        s16x8 c1 = *(const s16x8*)(tbase + 64 * 8);
        s16x8 c2 = *(const s16x8*)(tbase + 128 * 8);
        s16x8 c3 = *(const s16x8*)(tbase + 192 * 8);
        #pragma unroll 1
        for (int T = 0; T < NTILE; ++T) {
            const int Tn = (T + 1) & (NTILE - 1);
            const size_t nb = (size_t)Tn * 256 * 8;
            const s16x8 n0 = *(const s16x8*)(tbase + nb);
            const s16x8 n1 = *(const s16x8*)(tbase + nb + 64 * 8);
            const s16x8 n2 = *(const s16x8*)(tbase + nb + 128 * 8);
            const s16x8 n3 = *(const s16x8*)(tbase + nb + 192 * 8);
            f32x4 a0 = {0.f, 0.f, 0.f, 0.f};
            f32x4 a1 = {0.f, 0.f, 0.f, 0.f};
            a0 = __builtin_amdgcn_mfma_f32_16x16x32_bf16(afr[0], c0, a0, 0, 0, 0);
            a0 = __builtin_amdgcn_mfma_f32_16x16x32_bf16(afr[1], c1, a0, 0, 0, 0);
            a1 = __builtin_amdgcn_mfma_f32_16x16x32_bf16(afr[2], c2, a1, 0, 0, 0);
            a1 = __builtin_amdgcn_mfma_f32_16x16x32_bf16(afr[3], c3, a1, 0, 0, 0);
            const float sn = snorm[T * 16 + lm];
            const int code = T * 16 + lm;
            #pragma unroll
            for (int r = 0; r < 4; ++r) {
                const float t = fmaf(-2.f, a0[r] + a1[r], sn);
                if (t <= gm[r] + TH) {
                    const int prow = pxbase + lg * 4 + r;   // C/D row -> pixel
                    const int slot = atomicAdd(&s_cnt[prow], 1);
                    if (slot < CAP) s_ck[prow][slot] = code;
                }
            }
            c0 = n0; c1 = n1; c2 = n2; c3 = n3;
        }
    }
    __syncthreads();

    // ---- exact refinement (waves 0-1): ref chains verbatim ----
    if (ky < 2) {
        const int p = ky * 64 + px;
        // A: sequential over d (value cancels per-pixel; chain kept honest).
        const float z0 = s_zT[p][0];
        float A32 = fmul_x(z0, z0);
        for (int d = 1; d < D_DIM; ++d) {
            const float zd = s_zT[p][d];
            A32 = fadd_x(A32, fmul_x(zd, zd));
        }

        float bestq = __builtin_inff(); int bestk = 0x7fffffff;
        const int cnt = s_cnt[p];
        if (cnt <= CAP) {
            for (int i = 0; i < cnt; ++i) {
                const int kc = s_ck[p][i];
                const float* e = emb + (size_t)kc * D_DIM;
                float B32 = 0.f;
                for (int d = 0; d < D_DIM; ++d)
                    B32 = ffma_x(s_zT[p][d], e[d], B32);
                const float twoB = fmul_x(2.0f, B32);          // exact
                const float q    = fadd_x(fsub_x(A32, twoB), snorm[kc]);
                if (q < bestq || (q == bestq && kc < bestk)) { bestq = q; bestk = kc; }
            }
        } else {
            // worklist overflow (P ~ 1e-10/px): exact full scan, still correct
            for (int kc = 0; kc < K_CODES; ++kc) {
                const float* e = emb + (size_t)kc * D_DIM;
                float B32 = 0.f;
                for (int d = 0; d < D_DIM; ++d)
                    B32 = ffma_x(s_zT[p][d], e[d], B32);
                const float twoB = fmul_x(2.0f, B32);
                const float q    = fadd_x(fsub_x(A32, twoB), snorm[kc]);
                if (q < bestq || (q == bestq && kc < bestk)) { bestq = q; bestk = kc; }
            }
        }
        s_kwin[p] = bestk;
    }
    __syncthreads();

    // ---- epilogue: out0 = fl(fl(e-z)+z) (pinned), out1 = e ----
    const int p  = tid & 127;                   // pixel
    const int dg = tid >> 7;                    // d-quarter 0..3
    const int kwin = s_kwin[p];
    const float* er = emb + (size_t)kwin * D_DIM + dg * 32;
    float* o0 = out + (size_t)b * (D_DIM * HW_SZ) + hw0 + p;
    float* o1 = o0 + OUT_OFF;
    #pragma unroll
    for (int i = 0; i < 8; ++i) {
        const f32x4 e4 = *(const f32x4*)(er + i * 4);
        #pragma unroll
        for (int j = 0; j < 4; ++j) {
            const int d = dg * 32 + i * 4 + j;
            const float zv = s_zT[p][d];
            o0[(size_t)d * HW_SZ] = fadd_x(fsub_x(e4[j], zv), zv);
            o1[(size_t)d * HW_SZ] = e4[j];
        }
    }
}

extern "C" void kernel_launch(void* const* d_in, const int* in_sizes, int n_in,
                              void* d_out, int out_size, void* d_ws, size_t ws_size,
                              hipStream_t stream)
{
    const float* z_e = (const float*)d_in[0];
    const float* emb = (const float*)d_in[1];
    float* out = (float*)d_out;
    unsigned short* ebt = (unsigned short*)d_ws;
    (void)in_sizes; (void)n_in; (void)out_size; (void)ws_size;

    conv_ebf<<<dim3(64), dim3(256), 0, stream>>>(emb, ebt);
    vq_fused<<<dim3(N_PIX / PXB), dim3(64, NW), 0, stream>>>(z_e, emb, ebt, out);
}